// Round 1
// baseline (3056.317 us; speedup 1.0000x reference)
//
#include <hip/hip_runtime.h>

// out[idx, j] += src[i, j], out initialized from input.
// input: [65536, 64] f32; index: [1e6, 64] int32; src: [1e6, 64] f32.

__global__ void ScatterInit_kernel(const float4* __restrict__ in,
                                   float4* __restrict__ out, int n4) {
    int i = blockIdx.x * blockDim.x + threadIdx.x;
    if (i < n4) out[i] = in[i];
}

__global__ void ScatterAdd_kernel(const int4* __restrict__ index4,
                                  const float4* __restrict__ src4,
                                  float* __restrict__ out,
                                  int n4) {
    const int stride = gridDim.x * blockDim.x;
    for (int i = blockIdx.x * blockDim.x + threadIdx.x; i < n4; i += stride) {
        int4 idx = index4[i];
        float4 v  = src4[i];
        // D=64 and 4 | 64, so the 4 elements of this vector share a row of
        // the [N_SRC, 64] layout; column of element 0 is (i*4) % 64.
        int jbase = (i & 15) << 2;
        atomicAdd(&out[(idx.x << 6) + jbase + 0], v.x);
        atomicAdd(&out[(idx.y << 6) + jbase + 1], v.y);
        atomicAdd(&out[(idx.z << 6) + jbase + 2], v.z);
        atomicAdd(&out[(idx.w << 6) + jbase + 3], v.w);
    }
}

extern "C" void kernel_launch(void* const* d_in, const int* in_sizes, int n_in,
                              void* d_out, int out_size, void* d_ws, size_t ws_size,
                              hipStream_t stream) {
    const float* input = (const float*)d_in[0];
    const int*   index = (const int*)d_in[1];
    const float* src   = (const float*)d_in[2];
    float* out = (float*)d_out;

    // 1) out = input  (must fully overwrite the poisoned d_out every call)
    int n_out4 = out_size / 4;                 // 4,194,304 / 4 = 1,048,576
    int init_blocks = (n_out4 + 255) / 256;
    ScatterInit_kernel<<<init_blocks, 256, 0, stream>>>(
        (const float4*)input, (float4*)out, n_out4);

    // 2) scatter-add src into out
    int n_src = in_sizes[2];                   // 64,000,000
    int n4 = n_src / 4;                        // 16,000,000 (exact)
    int blocks = 2048;                         // 8 blocks/CU -> 32 waves/CU
    ScatterAdd_kernel<<<blocks, 256, 0, stream>>>(
        (const int4*)index, (const float4*)src, out, n4);
}

// Round 2
// 831.797 us; speedup vs baseline: 3.6744x; 3.6744x over previous
//
#include <hip/hip_runtime.h>

// out = input; out[index[i,j], j] += src[i,j]
// input: [65536,64] f32 ; index: [1e6,64] i32 ; src: [1e6,64] f32
// Strategy: counting-sort into 256 row-buckets (256 rows x 64 cols = 64KB tile),
// then per-bucket LDS reduction. Avoids 64M random device-scope atomics.

typedef unsigned int u32;
typedef unsigned long long u64;

#define NB2 1024        // blocks in hist/scatter passes
#define NBKT 256        // buckets (row >> 8)
#define CAP 16          // staged pairs per bucket per batch
#define CSTRIDE 17      // padded LDS stride (bank spread)
#define TILE 16384      // floats per bucket tile (256 rows * 64 cols)
#define QRED 2          // reduce blocks per bucket

__global__ void InitOut_kernel(const float4* __restrict__ in, float4* __restrict__ out, int n4) {
    int i = blockIdx.x * blockDim.x + threadIdx.x;
    if (i < n4) out[i] = in[i];
}

// ---------------- fallback (small ws): direct atomics ----------------
__global__ void FallbackAdd_kernel(const int4* __restrict__ index4,
                                   const float4* __restrict__ src4,
                                   float* __restrict__ out, int n4) {
    const int stride = gridDim.x * blockDim.x;
    for (int i = blockIdx.x * blockDim.x + threadIdx.x; i < n4; i += stride) {
        int4 idx = index4[i];
        float4 v = src4[i];
        int jbase = (i & 15) << 2;
        atomicAdd(&out[(idx.x << 6) + jbase + 0], v.x);
        atomicAdd(&out[(idx.y << 6) + jbase + 1], v.y);
        atomicAdd(&out[(idx.z << 6) + jbase + 2], v.z);
        atomicAdd(&out[(idx.w << 6) + jbase + 3], v.w);
    }
}

// ---------------- pass 1: per-(block,bucket) histogram ----------------
__global__ __launch_bounds__(256) void Hist_kernel(const int* __restrict__ index, u32* __restrict__ H,
                                                   long long E0, int EPB, long long Eend) {
    __shared__ u32 h[NBKT];
    int t = threadIdx.x, blk = blockIdx.x;
    h[t] = 0;
    __syncthreads();
    long long e0 = E0 + (long long)blk * EPB;
    long long e1 = e0 + EPB; if (e1 > Eend) e1 = Eend;
    for (long long e = e0 + t * 4; e < e1; e += 1024) {
        int4 idx = *(const int4*)(index + e);
        atomicAdd(&h[idx.x >> 8], 1u);
        atomicAdd(&h[idx.y >> 8], 1u);
        atomicAdd(&h[idx.z >> 8], 1u);
        atomicAdd(&h[idx.w >> 8], 1u);
    }
    __syncthreads();
    H[(size_t)t * NB2 + blk] = h[t];
}

// ---------------- scan: within-bucket across blocks ----------------
__global__ __launch_bounds__(256) void ScanBlocks_kernel(u32* __restrict__ H, u32* __restrict__ T) {
    int b = blockIdx.x, t = threadIdx.x;
    const int PER = NB2 / 256;
    u32* row = H + (size_t)b * NB2;
    u32 v[PER]; u32 s = 0;
    for (int i = 0; i < PER; ++i) { v[i] = row[t * PER + i]; s += v[i]; }
    __shared__ u32 ls[256];
    ls[t] = s;
    __syncthreads();
    for (int off = 1; off < 256; off <<= 1) {
        u32 y = (t >= off) ? ls[t - off] : 0;
        __syncthreads();
        ls[t] += y;
        __syncthreads();
    }
    u32 excl = ls[t] - s;
    for (int i = 0; i < PER; ++i) { row[t * PER + i] = excl; excl += v[i]; }
    if (t == 255) T[b] = ls[255];
}

// ---------------- scan: bucket starts ----------------
__global__ __launch_bounds__(256) void ScanBuckets_kernel(const u32* __restrict__ T, u32* __restrict__ S) {
    int t = threadIdx.x;
    u32 s = T[t];
    __shared__ u32 ls[256];
    ls[t] = s;
    __syncthreads();
    for (int off = 1; off < 256; off <<= 1) {
        u32 y = (t >= off) ? ls[t - off] : 0;
        __syncthreads();
        ls[t] += y;
        __syncthreads();
    }
    S[t] = ls[t] - s;
    if (t == 255) S[256] = ls[255];
}

// ---------------- pass 2: scatter pairs into bucketed scratch ----------------
__global__ __launch_bounds__(256) void Scatter_kernel(const int* __restrict__ index,
        const float* __restrict__ src, u64* __restrict__ pairs,
        const u32* __restrict__ O, const u32* __restrict__ S,
        long long E0, int EPB, long long Eend) {
    __shared__ u32 cnt[NBKT];
    __shared__ u32 basew[NBKT];
    __shared__ u64 stage[NBKT * CSTRIDE];   // ~34.8 KB
    int t = threadIdx.x, blk = blockIdx.x;
    basew[t] = S[t] + O[(size_t)t * NB2 + blk];
    cnt[t] = 0;
    __syncthreads();
    long long e0 = E0 + (long long)blk * EPB;
    long long e1 = e0 + EPB; if (e1 > Eend) e1 = Eend;
    for (long long eb = e0; eb < e1; eb += 2048) {
        long long e = eb + t * 8;
        if (e < e1) {   // per-block count is a multiple of 8, so all 8 valid
            int4 ia = *(const int4*)(index + e);
            float4 va = *(const float4*)(src + e);
            int4 ib = *(const int4*)(index + e + 4);
            float4 vb = *(const float4*)(src + e + 4);
            int col = (int)(e & 63);
#define PROC(r, val, c) { \
            int bb = (r) >> 8; \
            u32 p = atomicAdd(&cnt[bb], 1u); \
            u64 pr = ((u64)__float_as_uint(val) << 32) | (u32)(((r) << 6) + (c)); \
            if (p < CAP) stage[bb * CSTRIDE + p] = pr; \
            else pairs[(size_t)(basew[bb] + p)] = pr; }
            PROC(ia.x, va.x, col + 0); PROC(ia.y, va.y, col + 1);
            PROC(ia.z, va.z, col + 2); PROC(ia.w, va.w, col + 3);
            PROC(ib.x, vb.x, col + 4); PROC(ib.y, vb.y, col + 5);
            PROC(ib.z, vb.z, col + 6); PROC(ib.w, vb.w, col + 7);
#undef PROC
        }
        __syncthreads();
        {   // flush: thread t owns bucket t
            u32 c = cnt[t];
            u32 bs = basew[t];
            u32 n = c < CAP ? c : CAP;
            for (u32 i = 0; i < n; ++i) pairs[(size_t)(bs + i)] = stage[t * CSTRIDE + i];
            basew[t] = bs + c;
            cnt[t] = 0;
        }
        __syncthreads();
    }
}

// ---------------- pass 3: per-bucket LDS reduce, add into out ----------------
__global__ __launch_bounds__(256) void Reduce_kernel(const u64* __restrict__ pairs,
                                                     const u32* __restrict__ S,
                                                     float* __restrict__ out) {
    __shared__ float tile[TILE];            // 64 KB
    int b = blockIdx.x >> 1;                // QRED = 2
    int p = blockIdx.x & 1;
    int t = threadIdx.x;
    u32 s0 = S[b], s1 = S[b + 1];
    u32 half = (s1 - s0) >> 1;
    u32 a0 = p ? (s0 + half) : s0;
    u32 a1 = p ? s1 : (s0 + half);
    for (int i = t; i < TILE; i += 256) tile[i] = 0.f;
    __syncthreads();
    for (u32 i = a0 + t; i < a1; i += 256) {
        u64 pr = pairs[i];
        float v = __uint_as_float((u32)(pr >> 32));
        atomicAdd(&tile[(u32)pr & (TILE - 1)], v);
    }
    __syncthreads();
    float* ob = out + (size_t)b * TILE;
    for (int i = t; i < TILE; i += 256) atomicAdd(&ob[i], tile[i]);
}

extern "C" void kernel_launch(void* const* d_in, const int* in_sizes, int n_in,
                              void* d_out, int out_size, void* d_ws, size_t ws_size,
                              hipStream_t stream) {
    const float* input = (const float*)d_in[0];
    const int*   index = (const int*)d_in[1];
    const float* src   = (const float*)d_in[2];
    float* out = (float*)d_out;
    long long E = (long long)in_sizes[2];          // 64,000,000 elements

    // out = input (d_out is poisoned every timing run)
    int n4 = out_size / 4;
    InitOut_kernel<<<(n4 + 255) / 256, 256, 0, stream>>>(
        (const float4*)input, (float4*)out, n4);

    // workspace layout: [0,1MB) offsets O; [1MB) totals T; [1MB+4KB) starts S; [2MB) pairs
    const size_t META = 2u << 20;
    char* ws = (char*)d_ws;
    u32* O = (u32*)ws;
    u32* T = (u32*)(ws + (1u << 20));
    u32* S = (u32*)(ws + (1u << 20) + 4096);
    u64* pairs = (u64*)(ws + META);

    long long eprmax = 0;
    if (ws_size > META)
        eprmax = (long long)((ws_size - META) / 8) / 8192 * 8192;  // multiple of NB2*8

    if (eprmax < (8ll << 20)) {
        // ws too small for binning — direct atomic fallback
        FallbackAdd_kernel<<<2048, 256, 0, stream>>>(
            (const int4*)index, (const float4*)src, out, (int)(E / 4));
        return;
    }

    long long epr = E < eprmax ? E : eprmax;
    for (long long E0 = 0; E0 < E; E0 += epr) {
        long long Eend = (E0 + epr < E) ? (E0 + epr) : E;
        long long Er = Eend - E0;
        int EPB = (int)((Er + (long long)NB2 * 8 - 1) / ((long long)NB2 * 8)) * 8;
        Hist_kernel<<<NB2, 256, 0, stream>>>(index, O, E0, EPB, Eend);
        ScanBlocks_kernel<<<NBKT, 256, 0, stream>>>(O, T);
        ScanBuckets_kernel<<<1, 256, 0, stream>>>(T, S);
        Scatter_kernel<<<NB2, 256, 0, stream>>>(index, src, pairs, O, S, E0, EPB, Eend);
        Reduce_kernel<<<NBKT * QRED, 256, 0, stream>>>(pairs, S, out);
    }
}

// Round 3
// 766.553 us; speedup vs baseline: 3.9871x; 1.0851x over previous
//
#include <hip/hip_runtime.h>

// out = input; out[index[i,j], j] += src[i,j]
// input: [65536,64] f32 ; index: [1e6,64] i32 ; src: [1e6,64] f32
// Counting-sort into 256 row-buckets (SoA: f32 value + u16 local dest),
// then per-bucket LDS reduce fused with out = input + tile.

typedef unsigned int u32;
typedef unsigned short u16;

#define NB 1024         // blocks in hist/scatter passes
#define NBKT 256        // buckets (row >> 8)
#define CAP 24          // staged pairs per bucket per batch
#define BSZ 4096        // elements per block-batch (16/thread)
#define TILE 16384      // floats per bucket tile (256 rows * 64 cols)

// ---------------- fallback path ----------------
__global__ void InitOut_kernel(const float4* __restrict__ in, float4* __restrict__ out, int n4) {
    int i = blockIdx.x * blockDim.x + threadIdx.x;
    if (i < n4) out[i] = in[i];
}

__global__ void FallbackAdd_kernel(const int4* __restrict__ index4,
                                   const float4* __restrict__ src4,
                                   float* __restrict__ out, int n4) {
    const int stride = gridDim.x * blockDim.x;
    for (int i = blockIdx.x * blockDim.x + threadIdx.x; i < n4; i += stride) {
        int4 idx = index4[i];
        float4 v = src4[i];
        int jbase = (i & 15) << 2;
        atomicAdd(&out[(idx.x << 6) + jbase + 0], v.x);
        atomicAdd(&out[(idx.y << 6) + jbase + 1], v.y);
        atomicAdd(&out[(idx.z << 6) + jbase + 2], v.z);
        atomicAdd(&out[(idx.w << 6) + jbase + 3], v.w);
    }
}

// ---------------- pass 1: per-(bucket,block) histogram ----------------
__global__ __launch_bounds__(256) void Hist_kernel(const int* __restrict__ index,
                                                   u32* __restrict__ H,
                                                   int EPB, long long E) {
    __shared__ u32 h[NBKT];
    int t = threadIdx.x, blk = blockIdx.x;
    h[t] = 0;
    __syncthreads();
    long long e0 = (long long)blk * EPB;
    long long e1 = e0 + EPB; if (e1 > E) e1 = E;
    for (long long e = e0 + t * 4; e < e1; e += 1024) {
        int4 r = *(const int4*)(index + e);
        atomicAdd(&h[r.x >> 8], 1u);
        atomicAdd(&h[r.y >> 8], 1u);
        atomicAdd(&h[r.z >> 8], 1u);
        atomicAdd(&h[r.w >> 8], 1u);
    }
    __syncthreads();
    H[(size_t)t * NB + blk] = h[t];
}

// ---------------- scan: within-bucket across blocks ----------------
__global__ __launch_bounds__(256) void ScanBlocks_kernel(u32* __restrict__ H, u32* __restrict__ T) {
    int b = blockIdx.x, t = threadIdx.x;
    const int PER = NB / 256;
    u32* row = H + (size_t)b * NB;
    u32 v[PER]; u32 s = 0;
    for (int i = 0; i < PER; ++i) { v[i] = row[t * PER + i]; s += v[i]; }
    __shared__ u32 ls[256];
    ls[t] = s;
    __syncthreads();
    for (int off = 1; off < 256; off <<= 1) {
        u32 y = (t >= off) ? ls[t - off] : 0;
        __syncthreads();
        ls[t] += y;
        __syncthreads();
    }
    u32 excl = ls[t] - s;
    for (int i = 0; i < PER; ++i) { row[t * PER + i] = excl; excl += v[i]; }
    if (t == 255) T[b] = ls[255];
}

// ---------------- scan: bucket starts (padded to x4 for vector loads) ----------------
__global__ __launch_bounds__(256) void ScanBuckets_kernel(const u32* __restrict__ T, u32* __restrict__ S) {
    int t = threadIdx.x;
    u32 s = (T[t] + 3u) & ~3u;   // pad each bucket to multiple of 4 pairs
    __shared__ u32 ls[256];
    ls[t] = s;
    __syncthreads();
    for (int off = 1; off < 256; off <<= 1) {
        u32 y = (t >= off) ? ls[t - off] : 0;
        __syncthreads();
        ls[t] += y;
        __syncthreads();
    }
    S[t] = ls[t] - s;
    if (t == 255) S[256] = ls[255];
}

// ---------------- pass 2: scatter SoA pairs into bucketed scratch ----------------
__global__ __launch_bounds__(256) void Scatter_kernel(const int* __restrict__ index,
        const float* __restrict__ src,
        float* __restrict__ val, u16* __restrict__ dst,
        const u32* __restrict__ O, const u32* __restrict__ S,
        int EPB, long long E) {
    __shared__ float stage_v[NBKT * CAP];   // 24 KB
    __shared__ u16  stage_d[NBKT * CAP];    // 12 KB
    __shared__ u32 cnt[NBKT];
    __shared__ u32 basew[NBKT];
    int t = threadIdx.x, blk = blockIdx.x;
    basew[t] = S[t] + O[(size_t)t * NB + blk];
    cnt[t] = 0;
    __syncthreads();
    long long e0 = (long long)blk * EPB;
    long long e1 = e0 + EPB; if (e1 > E) e1 = E;
    for (long long eb = e0; eb < e1; eb += BSZ) {
#define PROC(rr, vv, cc) { \
        int bb = (rr) >> 8; \
        u32 p = atomicAdd(&cnt[bb], 1u); \
        u16 dd = (u16)((((rr) & 255) << 6) | (cc)); \
        if (p < CAP) { stage_v[bb * CAP + p] = (vv); stage_d[bb * CAP + p] = dd; } \
        else { u32 pos = basew[bb] + p; val[pos] = (vv); dst[pos] = dd; } }
        for (int g = 0; g < BSZ / 1024; ++g) {
            long long e = eb + g * 1024 + t * 4;
            if (e < e1) {
                int4 r = *(const int4*)(index + e);
                float4 v = *(const float4*)(src + e);
                int col = (int)(e & 63);
                PROC(r.x, v.x, col + 0); PROC(r.y, v.y, col + 1);
                PROC(r.z, v.z, col + 2); PROC(r.w, v.w, col + 3);
            }
        }
#undef PROC
        __syncthreads();
        {   // cooperative flush: 8 threads per bucket, 32 buckets per pass
            int bq = t >> 3, rr = t & 7;
            for (int pp = 0; pp < 8; ++pp) {
                int b = pp * 32 + bq;
                u32 c = cnt[b]; if (c > CAP) c = CAP;
                u32 bs = basew[b];
                for (u32 i = rr; i < c; i += 8) {
                    val[bs + i] = stage_v[b * CAP + i];
                    dst[bs + i] = stage_d[b * CAP + i];
                }
            }
        }
        __syncthreads();
        basew[t] += cnt[t];
        cnt[t] = 0;
        __syncthreads();
    }
}

// ---------------- pass 3: per-bucket LDS reduce + out = input + tile ----------------
__global__ __launch_bounds__(1024) void Reduce_kernel(const float* __restrict__ val,
                                                      const u16* __restrict__ dst,
                                                      const u32* __restrict__ S,
                                                      const u32* __restrict__ T,
                                                      const float* __restrict__ input,
                                                      float* __restrict__ out) {
    __shared__ float tile[TILE];            // 64 KB
    int b = blockIdx.x, t = threadIdx.x;
    float4* t4 = (float4*)tile;
    for (int i = t; i < TILE / 4; i += 1024) t4[i] = make_float4(0.f, 0.f, 0.f, 0.f);
    __syncthreads();
    u32 s0 = S[b];
    u32 n = T[b];
    const float4* v4 = (const float4*)(val + s0);
    const ushort4* d4 = (const ushort4*)(dst + s0);
    u32 n4 = n >> 2;
    for (u32 i = t; i < n4; i += 1024) {
        float4 v = v4[i]; ushort4 d = d4[i];
        atomicAdd(&tile[d.x], v.x);
        atomicAdd(&tile[d.y], v.y);
        atomicAdd(&tile[d.z], v.z);
        atomicAdd(&tile[d.w], v.w);
    }
    for (u32 i = (n4 << 2) + t; i < n; i += 1024) {
        atomicAdd(&tile[dst[s0 + i]], val[s0 + i]);
    }
    __syncthreads();
    const float4* in4 = (const float4*)(input + (size_t)b * TILE);
    float4* o4 = (float4*)(out + (size_t)b * TILE);
    for (int i = t; i < TILE / 4; i += 1024) {
        float4 a = in4[i], sgm = t4[i];
        a.x += sgm.x; a.y += sgm.y; a.z += sgm.z; a.w += sgm.w;
        o4[i] = a;
    }
}

extern "C" void kernel_launch(void* const* d_in, const int* in_sizes, int n_in,
                              void* d_out, int out_size, void* d_ws, size_t ws_size,
                              hipStream_t stream) {
    const float* input = (const float*)d_in[0];
    const int*   index = (const int*)d_in[1];
    const float* src   = (const float*)d_in[2];
    float* out = (float*)d_out;
    long long E = (long long)in_sizes[2];          // 64,000,000

    // ws layout: O (1MB) | T (1KB) | S (1KB+) | val (f32, E+pad) | dst (u16, E+pad)
    char* ws = (char*)d_ws;
    u32* O = (u32*)ws;
    u32* T = (u32*)(ws + (1u << 20));
    u32* S = (u32*)(ws + (1u << 20) + 4096);
    size_t offV = (size_t)2u << 20;
    size_t nPad = (size_t)E + 4 * NBKT;
    size_t offD = offV + ((nPad * 4 + 65535) & ~(size_t)65535);
    size_t need = offD + nPad * 2;

    if (ws_size < need || (E & 3) || out_size != NBKT * TILE) {
        // fallback: direct atomics
        int n4o = out_size / 4;
        InitOut_kernel<<<(n4o + 255) / 256, 256, 0, stream>>>(
            (const float4*)input, (float4*)out, n4o);
        FallbackAdd_kernel<<<2048, 256, 0, stream>>>(
            (const int4*)index, (const float4*)src, out, (int)(E / 4));
        return;
    }

    float* val = (float*)(ws + offV);
    u16*  dst = (u16*)(ws + offD);
    int EPB = (int)((E + (long long)NB * 4 - 1) / ((long long)NB * 4)) * 4;

    Hist_kernel<<<NB, 256, 0, stream>>>(index, O, EPB, E);
    ScanBlocks_kernel<<<NBKT, 256, 0, stream>>>(O, T);
    ScanBuckets_kernel<<<1, 256, 0, stream>>>(T, S);
    Scatter_kernel<<<NB, 256, 0, stream>>>(index, src, val, dst, O, S, EPB, E);
    Reduce_kernel<<<NBKT, 1024, 0, stream>>>(val, dst, S, T, input, out);
}